// Round 8
// baseline (184.554 us; speedup 1.0000x reference)
//
#include <hip/hip_runtime.h>
#include <hip/hip_bf16.h>

// SelfAttentionLocal: N=1024, DIM=512, H=8, hd=64. Inputs f32, output f32.
// 2 kernels: [union: cvt blocks (0..1279) | loc blocks | proj blocks (gated on
// cvt via device-scope flag)] -> [split-K MFMA flash].
// L stores t = relu(loc)+1e-6 (not log t); k_mha multiplies t after the exp.
// R8: k_cvt folded into the union kernel as independent blocks; proj blocks
// acquire-spin on a completion flag (<=384 spinners vs ~2048 resident slots ->
// progress guaranteed regardless of dispatch order). Loc blocks self-compute
// box features from locs (no prep dependency) and repack W_loc in-register.
// Loc MFMA path, proj tile, k_mha = R7 (best, 50.5us).

namespace {
constexpr int NN   = 1024;
constexpr int CDIM = 512;
constexpr int NH   = 8;
constexpr int HD   = 64;
constexpr int NOUT = 3 * CDIM;  // 1536 projection output features
constexpr int CVT_BLOCKS  = 1280;  // (NN*CDIM + NOUT*CDIM)/1024
constexpr int LOC_BLOCKS  = 4096;
constexpr int PROJ_BLOCKS = (NN / 64) * (NOUT / 64);  // 384
constexpr float QSCALE = 0.125f;  // (512/8)^-0.5

// ws layout (u16 units)
constexpr size_t QKBF_OFF_U16 = 0;                                   // 2*8*1024*64
constexpr size_t VT_OFF_U16   = (size_t)2 * NH * NN * HD;            // [h][d][n]
constexpr size_t XB_OFF_U16   = VT_OFF_U16 + (size_t)NH * HD * NN;
constexpr size_t WB_OFF_U16   = XB_OFF_U16 + (size_t)NN * CDIM;
constexpr size_t L_OFF_U16    = WB_OFF_U16 + (size_t)NOUT * CDIM;    // 2,883,584
constexpr size_t END_U16      = L_OFF_U16 + (size_t)NH * NN * NN;    // 11,272,192
constexpr size_t FLAG_OFF_B   = END_U16 * 2;                         // 4B, 4-aligned
}

typedef __attribute__((ext_vector_type(8))) short short8v;   // 8 bf16 (4 VGPR)
typedef __attribute__((ext_vector_type(4))) float f32x4;

__device__ __forceinline__ unsigned short f2bf(float f) {
  union { float f; unsigned int u; } v; v.f = f;
  unsigned int u = v.u;
  u += 0x7fffu + ((u >> 16) & 1u);  // RNE
  return (unsigned short)(u >> 16);
}
__device__ __forceinline__ float b2f(unsigned short u) {
  union { unsigned int u; float f; } v; v.u = ((unsigned int)u) << 16; return v.f;
}

// ---------------- K1: union — cvt | loc | proj(gated) ---------------------
__global__ __launch_bounds__(256) void k_union(const float* __restrict__ x,
                                               const float* __restrict__ wq,
                                               const float* __restrict__ locs,
                                               const float* __restrict__ wloc,
                                               const float* __restrict__ bloc,
                                               unsigned short* __restrict__ xb,
                                               unsigned short* __restrict__ wb,
                                               unsigned short* __restrict__ qk_bf,
                                               unsigned short* __restrict__ vt,
                                               unsigned short* __restrict__ L,
                                               unsigned int* __restrict__ flag) {
  __shared__ unsigned short A_lds[64][72];
  __shared__ unsigned short B_lds[64][72];
  int blk = blockIdx.x;
  int tid = threadIdx.x;

  if (blk < CVT_BLOCKS) {
    // ---- cvt block: f32 -> bf16 for x and Wqkv (convert ONCE) ----
    constexpr int XTOT = NN * CDIM;  // 524288
    int idx = (blk * 256 + tid) * 4;
    if (idx < XTOT) {
      float4 v = *reinterpret_cast<const float4*>(x + idx);
      ushort4 o;
      o.x = f2bf(v.x); o.y = f2bf(v.y); o.z = f2bf(v.z); o.w = f2bf(v.w);
      *reinterpret_cast<ushort4*>(xb + idx) = o;
    } else {
      int j = idx - XTOT;
      float4 v = *reinterpret_cast<const float4*>(wq + j);
      ushort4 o;
      o.x = f2bf(v.x); o.y = f2bf(v.y); o.z = f2bf(v.z); o.w = f2bf(v.w);
      *reinterpret_cast<ushort4*>(wb + j) = o;
    }
    // release: stores visible device-wide, then bump the flag
    __threadfence();
    __syncthreads();
    if (tid == 0) {
      __hip_atomic_fetch_add(flag, 1u, __ATOMIC_RELEASE, __HIP_MEMORY_SCOPE_AGENT);
    }
  } else if (blk < CVT_BLOCKS + LOC_BLOCKS) {
    // ---- loc block: one n-row, 256 m; wave w owns m in [m0+64w, +64) ----
    // Self-contained: box features from locs, W_loc repacked in-register.
    int blk2 = blk - CVT_BLOCKS;
    int n = blk2 >> 2;
    int m0 = (blk2 & 3) * 256;
    int w = tid >> 6, l = tid & 63, g = l >> 4, c = l & 15;

    // n-side features (wave-uniform)
    float4 bn = reinterpret_cast<const float4*>(locs)[n];
    float wn = bn.z - bn.x + 1.0f;
    float hn = bn.w - bn.y + 1.0f;
    float cxn = 0.5f * (bn.x + bn.z);
    float cyn = 0.5f * (bn.y + bn.w);
    float rwn = 1.0f / wn;
    float rhn = 1.0f / hn;
    float lwn = __logf(wn);
    float lhn = __logf(hn);

    // loop-invariant per-lane angles: ANG[t] = 100 * 1000^(-t/8)
    float ang0 = 100.0f * exp2f(-1.2457230355894468f * (float)g);  // t = g
    float ang1 = ang0 * 0.031622776601683794f;                     // t = g+4

    // A-frags from wloc (2KB, cache-hot): w2[c][f], f = 2*(4t+j)+sc maps to
    // wloc feature j*16 + sc*8 + t; rows c>=8 are zero padding.
    union AU { unsigned short us[8]; short8v v; } alo, ahi;
#pragma unroll
    for (int e = 0; e < 8; ++e) {
      int f0 = 8 * g + e;
      int f1 = 32 + 8 * g + e;
      int sc0 = f0 & 1, j0 = (f0 >> 1) & 3, tt0 = f0 >> 3;
      int sc1 = f1 & 1, j1 = (f1 >> 1) & 3, tt1 = f1 >> 3;
      alo.us[e] = (c < 8) ? f2bf(wloc[c * 64 + j0 * 16 + sc0 * 8 + tt0]) : (unsigned short)0;
      ahi.us[e] = (c < 8) ? f2bf(wloc[c * 64 + j1 * 16 + sc1 * 8 + tt1]) : (unsigned short)0;
    }
    // bias per D-row: head = 4g + r (rows 8..15 padding, masked at store)
    float br_[4];
#pragma unroll
    for (int r = 0; r < 4; ++r) br_[r] = bloc[(4 * g + r) & 7];

#pragma unroll
    for (int it = 0; it < 4; ++it) {
      int m = m0 + w * 64 + it * 16 + c;
      float4 bm = reinterpret_cast<const float4*>(locs)[m];
      float wm = bm.z - bm.x + 1.0f;
      float hm = bm.w - bm.y + 1.0f;
      float cxm = 0.5f * (bm.x + bm.z);
      float cym = 0.5f * (bm.y + bm.w);
      float dx = __logf(fmaxf(fabsf((cxn - cxm) * rwn), 1e-3f));
      float dy = __logf(fmaxf(fabsf((cyn - cym) * rhn), 1e-3f));
      float dwv = __logf(wm) - lwn;
      float dhv = __logf(hm) - lhn;
      float pos[4] = {dx, dy, dwv, dhv};

      // B-frags: element order within slice = [sin j, cos j] pairs, j=0..3
      union BU { unsigned int u[4]; short8v v; } b0, b1;
#pragma unroll
      for (int j = 0; j < 4; ++j) {
        float s0v, c0v, s1v, c1v;
        __sincosf(pos[j] * ang0, &s0v, &c0v);
        __sincosf(pos[j] * ang1, &s1v, &c1v);
        union { __hip_bfloat162 h; unsigned int u; } cv0, cv1;
        cv0.h = __float22bfloat162_rn(make_float2(s0v, c0v));
        cv1.h = __float22bfloat162_rn(make_float2(s1v, c1v));
        b0.u[j] = cv0.u;
        b1.u[j] = cv1.u;
      }

      f32x4 z = {0.f, 0.f, 0.f, 0.f};
      f32x4 acc4 = __builtin_amdgcn_mfma_f32_16x16x32_bf16(alo.v, b0.v, z, 0, 0, 0);
      acc4 = __builtin_amdgcn_mfma_f32_16x16x32_bf16(ahi.v, b1.v, acc4, 0, 0, 0);

      if (g < 2) {
#pragma unroll
        for (int r = 0; r < 4; ++r) {
          float v = fmaxf(acc4[r] + br_[r], 0.0f) + 1e-6f;
          L[((size_t)(4 * g + r) * NN + n) * NN + m] = f2bf(v);
        }
      }
    }
  } else {
    // ---- projection gemm tile (gated on cvt completion) ----
    // Acquire-spin: bounded spinners (384) << resident slots -> deadlock-free.
    while (__hip_atomic_load(flag, __ATOMIC_ACQUIRE, __HIP_MEMORY_SCOPE_AGENT)
           < (unsigned int)CVT_BLOCKS) {
      __builtin_amdgcn_s_sleep(8);
    }

    int t = blk - (CVT_BLOCKS + LOC_BLOCKS);
    int n0 = (t & 15) * 64, i0 = (t >> 4) * 64;
    int w = tid >> 6, l = tid & 63, g = l >> 4, c = l & 15;
    int sr = tid >> 2;            // stage row 0..63
    int sc = (tid & 3) * 16;      // stage col (u16)

    f32x4 acc[4];
#pragma unroll
    for (int ct = 0; ct < 4; ++ct) acc[ct] = (f32x4){0.f, 0.f, 0.f, 0.f};

    for (int kt = 0; kt < CDIM; kt += 64) {
      const unsigned short* asrc = xb + (size_t)(n0 + sr) * CDIM + kt + sc;
      const unsigned short* bsrc = wb + (size_t)(i0 + sr) * CDIM + kt + sc;
      *reinterpret_cast<short8v*>(&A_lds[sr][sc])     = *reinterpret_cast<const short8v*>(asrc);
      *reinterpret_cast<short8v*>(&A_lds[sr][sc + 8]) = *reinterpret_cast<const short8v*>(asrc + 8);
      *reinterpret_cast<short8v*>(&B_lds[sr][sc])     = *reinterpret_cast<const short8v*>(bsrc);
      *reinterpret_cast<short8v*>(&B_lds[sr][sc + 8]) = *reinterpret_cast<const short8v*>(bsrc + 8);
      __syncthreads();
#pragma unroll
      for (int kks = 0; kks < 2; ++kks) {
        short8v a = *reinterpret_cast<const short8v*>(&A_lds[16 * w + c][kks * 32 + 8 * g]);
#pragma unroll
        for (int ct = 0; ct < 4; ++ct) {
          short8v b = *reinterpret_cast<const short8v*>(&B_lds[16 * ct + c][kks * 32 + 8 * g]);
          acc[ct] = __builtin_amdgcn_mfma_f32_16x16x32_bf16(a, b, acc[ct], 0, 0, 0);
        }
      }
      __syncthreads();
    }

    int s = i0 >> 9;            // 0=q, 1=k, 2=v
    int hh = (i0 >> 6) & 7;
    if (s < 2) {
      float scale = (s == 0) ? QSCALE : 1.0f;
      unsigned short* dst = qk_bf + ((size_t)(s * NH + hh) * NN) * HD;
#pragma unroll
      for (int ct = 0; ct < 4; ++ct)
#pragma unroll
        for (int r = 0; r < 4; ++r) {
          int n = n0 + 16 * w + 4 * g + r;
          dst[(size_t)n * HD + 16 * ct + c] = f2bf(acc[ct][r] * scale);
        }
    } else {
      // v: transpose 64x64 tile via LDS, write vt[h][d][n] coalesced
#pragma unroll
      for (int ct = 0; ct < 4; ++ct)
#pragma unroll
        for (int r = 0; r < 4; ++r) {
          A_lds[16 * w + 4 * g + r][16 * ct + c] = f2bf(acc[ct][r]);
        }
      __syncthreads();
      int d = tid >> 2;             // 0..63
      int nn0 = (tid & 3) * 16;     // 16-wide n chunk
      unsigned short o[16];
#pragma unroll
      for (int nn = 0; nn < 16; ++nn) o[nn] = A_lds[nn0 + nn][d];
      unsigned short* dst = vt + ((size_t)hh * HD + d) * NN + n0 + nn0;
      *reinterpret_cast<short8v*>(dst)     = *reinterpret_cast<short8v*>(&o[0]);
      *reinterpret_cast<short8v*>(dst + 8) = *reinterpret_cast<short8v*>(&o[8]);
    }
  }
}

// ---------------- K2: split-K MFMA flash attention ------------------------
// 8 waves per (16-q-rows, head) block; wave w owns 128 keys. V staged to LDS
// per wave; LDS phase-unioned {V,P} <-> {accs,mls,scw,rlf} (barrier-guarded).
__global__ __launch_bounds__(512) void k_mha(const unsigned short* __restrict__ qk,
                                             const unsigned short* __restrict__ vt,
                                             const unsigned short* __restrict__ L,
                                             float* __restrict__ out) {
  __shared__ short8v smem16[3200];  // 51200 B
  auto V = reinterpret_cast<unsigned short(*)[64][40]>(smem16);                      // [8], 40960B
  auto P = reinterpret_cast<unsigned short(*)[640]>(
      reinterpret_cast<char*>(smem16) + 40960);                                      // [8], 10240B
  auto accs = reinterpret_cast<float(*)[16][68]>(smem16);                            // [8], 34816B
  auto mls = reinterpret_cast<float(*)[2][16]>(reinterpret_cast<char*>(smem16) + 34816);
  auto scw2 = reinterpret_cast<float(*)[16]>(reinterpret_cast<char*>(smem16) + 35840); // [8][16]
  auto rlf = reinterpret_cast<float*>(reinterpret_cast<char*>(smem16) + 36352);        // [16]

  int tid = threadIdx.x;
  int w = tid >> 6;      // wave id: key-chunk
  int l = tid & 63;
  int g = l >> 4;        // 16-lane group: k-quarter index
  int c = l & 15;        // col within fragment
  int h = blockIdx.y;
  int n0 = blockIdx.x * 16;

  const unsigned short* qb = qk + ((size_t)(0 * NH + h) * NN + n0) * HD;
  const unsigned short* kb = qk + ((size_t)(1 * NH + h) * NN) * HD;
  const unsigned short* vb = vt + (size_t)h * HD * NN;
  const unsigned short* Lb = L + ((size_t)h * NN + n0 + 4 * g) * NN;  // row 4g (+r via r*NN)

  // Q A-frags (loop-invariant): row=c, k(hd)=8g+b
  short8v a_lo = *reinterpret_cast<const short8v*>(qb + (size_t)c * HD + 8 * g);
  short8v a_hi = *reinterpret_cast<const short8v*>(qb + (size_t)c * HD + 32 + 8 * g);

  f32x4 acc[4];
#pragma unroll
  for (int ct = 0; ct < 4; ++ct) acc[ct] = (f32x4){0.f, 0.f, 0.f, 0.f};
  float m_run[4] = {-3.0e38f, -3.0e38f, -3.0e38f, -3.0e38f};
  float l_run[4] = {0.f, 0.f, 0.f, 0.f};

#pragma unroll
  for (int it = 0; it < 4; ++it) {
    int mt = w * 128 + it * 32;

    // stage this wave's V tile: V[w][d][key], coalesced 64B-row loads from vt
#pragma unroll
    for (int p = 0; p < 4; ++p) {
      int d = p * 16 + (l >> 2);
      int key16 = (l & 3) * 8;
      *reinterpret_cast<short8v*>(&V[w][d][key16]) =
          *reinterpret_cast<const short8v*>(vb + (size_t)d * NN + mt + key16);
    }

    // loc factors t = relu(loc)+1e-6 (bf16): prefetch before softmax
    float t0[4], t1[4];
#pragma unroll
    for (int r = 0; r < 4; ++r) {
      t0[r] = b2f(Lb[(size_t)r * NN + mt + c]);
      t1[r] = b2f(Lb[(size_t)r * NN + mt + 16 + c]);
    }

    // K B-frags: col(key)=c, k(hd)=8g+b
    const unsigned short* k0p = kb + (size_t)(mt + c) * HD + 8 * g;
    const unsigned short* k1p = kb + (size_t)(mt + 16 + c) * HD + 8 * g;
    short8v b0_lo = *reinterpret_cast<const short8v*>(k0p);
    short8v b0_hi = *reinterpret_cast<const short8v*>(k0p + 32);
    short8v b1_lo = *reinterpret_cast<const short8v*>(k1p);
    short8v b1_hi = *reinterpret_cast<const short8v*>(k1p + 32);

    __builtin_amdgcn_s_setprio(1);
    f32x4 z = {0.f, 0.f, 0.f, 0.f};
    f32x4 s0 = __builtin_amdgcn_mfma_f32_16x16x32_bf16(a_lo, b0_lo, z, 0, 0, 0);
    s0 = __builtin_amdgcn_mfma_f32_16x16x32_bf16(a_hi, b0_hi, s0, 0, 0, 0);
    f32x4 s1 = __builtin_amdgcn_mfma_f32_16x16x32_bf16(a_lo, b1_lo, z, 0, 0, 0);
    s1 = __builtin_amdgcn_mfma_f32_16x16x32_bf16(a_hi, b1_hi, s1, 0, 0, 0);
    __builtin_amdgcn_s_setprio(0);

    // online softmax over s only (t folded in multiplicatively). l_run is kept
    // as a PER-LANE partial (sc[r] is row-uniform) — reduced once at stash.
    float sc[4], p0[4], p1[4];
#pragma unroll
    for (int r = 0; r < 4; ++r) {
      float mx = fmaxf(s0[r], s1[r]);
      mx = fmaxf(mx, __shfl_xor(mx, 1));
      mx = fmaxf(mx, __shfl_xor(mx, 2));
      mx = fmaxf(mx, __shfl_xor(mx, 4));
      mx = fmaxf(mx, __shfl_xor(mx, 8));
      float m_new = fmaxf(m_run[r], mx);
      sc[r] = __expf(m_run[r] - m_new);
      p0[r] = t0[r] * __expf(s0[r] - m_new);
      p1[r] = t1[r] * __expf(s1[r] - m_new);
      l_run[r] = l_run[r] * sc[r] + (p0[r] + p1[r]);
      m_run[r] = m_new;
    }
#pragma unroll
    for (int ct = 0; ct < 4; ++ct)
#pragma unroll
      for (int r = 0; r < 4; ++r) acc[ct][r] *= sc[r];

    // P -> LDS (bf16), D-layout positions
#pragma unroll
    for (int r = 0; r < 4; ++r) {
      P[w][(4 * g + r) * 40 + c] = f2bf(p0[r]);
      P[w][(4 * g + r) * 40 + 16 + c] = f2bf(p1[r]);
    }
    __builtin_amdgcn_wave_barrier();

    // PV: A = P[16 rows][32 keys] (row=c, k=8g+b), B = V_lds col-tiles
    short8v pa = *reinterpret_cast<const short8v*>(&P[w][c * 40 + 8 * g]);
    __builtin_amdgcn_s_setprio(1);
#pragma unroll
    for (int ct = 0; ct < 4; ++ct) {
      short8v vbf = *reinterpret_cast<const short8v*>(&V[w][ct * 16 + c][8 * g]);
      acc[ct] = __builtin_amdgcn_mfma_f32_16x16x32_bf16(pa, vbf, acc[ct], 0, 0, 0);
    }
    __builtin_amdgcn_s_setprio(0);
    __builtin_amdgcn_wave_barrier();  // LDS reads done before next-iter writes
  }

  // deferred l reduce across the 16 lanes of each group
#pragma unroll
  for (int r = 0; r < 4; ++r) {
    float ls = l_run[r];
    ls += __shfl_xor(ls, 1);
    ls += __shfl_xor(ls, 2);
    ls += __shfl_xor(ls, 4);
    ls += __shfl_xor(ls, 8);
    l_run[r] = ls;
  }

  __syncthreads();  // all waves done with V/P before accs/mls overlay writes

  // stash partials
  if (c == 0) {
#pragma unroll
    for (int r = 0; r < 4; ++r) {
      mls[w][0][4 * g + r] = m_run[r];
      mls[w][1][4 * g + r] = l_run[r];
    }
  }
#pragma unroll
  for (int ct = 0; ct < 4; ++ct)
#pragma unroll
    for (int r = 0; r < 4; ++r) accs[w][4 * g + r][ct * 16 + c] = acc[ct][r];
  __syncthreads();

  // per-row merge factors, computed once (was per-output: 64x redundant)
  if (tid < 16) {
    int row = tid;
    float mfin = mls[0][0][row];
#pragma unroll
    for (int w2i = 1; w2i < 8; ++w2i) mfin = fmaxf(mfin, mls[w2i][0][row]);
    float lfin = 0.f;
#pragma unroll
    for (int w2i = 0; w2i < 8; ++w2i) {
      float scv = __expf(mls[w2i][0][row] - mfin);
      scw2[w2i][row] = scv;
      lfin += mls[w2i][1][row] * scv;
    }
    rlf[row] = 1.0f / lfin;
  }
  __syncthreads();

  // merge: 1024 outputs over 512 threads (2 each)
#pragma unroll
  for (int o = tid; o < 16 * 64; o += 512) {
    int row = o >> 6, col = o & 63;
    float val = 0.f;
#pragma unroll
    for (int w2i = 0; w2i < 8; ++w2i) {
      val += scw2[w2i][row] * accs[w2i][row][col];
    }
    out[(size_t)(n0 + row) * CDIM + h * HD + col] = val * rlf[row];
  }
}

extern "C" void kernel_launch(void* const* d_in, const int* in_sizes, int n_in,
                              void* d_out, int out_size, void* d_ws, size_t ws_size,
                              hipStream_t stream) {
  const float* x    = (const float*)d_in[0];
  // d_in[1] = x_reg: unused by the reference
  const float* locs = (const float*)d_in[2];
  const float* wqkv = (const float*)d_in[3];
  const float* wloc = (const float*)d_in[4];
  const float* bloc = (const float*)d_in[5];
  float* out = (float*)d_out;
  unsigned short* ws_u16 = (unsigned short*)d_ws;

  unsigned short* qk_bf = ws_u16 + QKBF_OFF_U16;
  unsigned short* vt_bf = ws_u16 + VT_OFF_U16;
  unsigned short* xb    = ws_u16 + XB_OFF_U16;
  unsigned short* wb    = ws_u16 + WB_OFF_U16;
  unsigned short* L     = ws_u16 + L_OFF_U16;
  unsigned int* flag    = (unsigned int*)((char*)d_ws + FLAG_OFF_B);

  hipMemsetAsync(flag, 0, sizeof(unsigned int), stream);
  k_union<<<dim3(CVT_BLOCKS + LOC_BLOCKS + PROJ_BLOCKS), dim3(256), 0, stream>>>(
      x, wqkv, locs, wloc, bloc, xb, wb, qk_bf, vt_bf, L, flag);
  k_mha<<<dim3(NN / 16, NH), dim3(512), 0, stream>>>(qk_bf, vt_bf, L, out);
}

// Round 9
// 64.026 us; speedup vs baseline: 2.8825x; 2.8825x over previous
//
#include <hip/hip_runtime.h>
#include <hip/hip_bf16.h>

// SelfAttentionLocal: N=1024, DIM=512, H=8, hd=64. Inputs f32, output f32.
// 3 kernels, zero intra-grid sync (R8's flag-gate spin poisoned the chip with
// acquire-invalidate traffic — 174us; reverted):
//   k1: cvt blocks (mem-bound) + prep block + loc[0..LOCA) self-contained
//       -> cvt hides under the loc VALU/trans pole.
//   k2: proj blocks (cvt ready via kernel boundary) + loc[LOCA..4096) table-
//       based -> proj hides under the remaining loc pole.
//   k3: split-K MFMA flash (R7, unchanged).
// L stores t = relu(loc)+1e-6 (not log t); k_mha multiplies t after the exp.

namespace {
constexpr int NN   = 1024;
constexpr int CDIM = 512;
constexpr int NH   = 8;
constexpr int HD   = 64;
constexpr int NOUT = 3 * CDIM;  // 1536 projection output features
constexpr int CVT_BLOCKS  = 1280;  // (NN*CDIM + NOUT*CDIM)/1024
constexpr int LOC_TOTAL   = 4096;
constexpr int LOCA        = 2048;  // loc blocks in k1 (self-contained)
constexpr int PROJ_BLOCKS = (NN / 64) * (NOUT / 64);  // 384
constexpr float QSCALE = 0.125f;  // (512/8)^-0.5

// ws layout (u16 units, then f32 region)
constexpr size_t QKBF_OFF_U16 = 0;                                   // 2*8*1024*64
constexpr size_t VT_OFF_U16   = (size_t)2 * NH * NN * HD;            // [h][d][n]
constexpr size_t XB_OFF_U16   = VT_OFF_U16 + (size_t)NH * HD * NN;
constexpr size_t WB_OFF_U16   = XB_OFF_U16 + (size_t)NN * CDIM;
constexpr size_t L_OFF_U16    = WB_OFF_U16 + (size_t)NOUT * CDIM;    // 2,883,584
constexpr size_t END_U16      = L_OFF_U16 + (size_t)NH * NN * NN;    // 11,272,192
constexpr size_t BF_OFF_F32   = END_U16 / 2;                         // 5,636,096
}

typedef __attribute__((ext_vector_type(8))) short short8v;   // 8 bf16 (4 VGPR)
typedef __attribute__((ext_vector_type(4))) float f32x4;

__device__ __forceinline__ unsigned short f2bf(float f) {
  union { float f; unsigned int u; } v; v.f = f;
  unsigned int u = v.u;
  u += 0x7fffu + ((u >> 16) & 1u);  // RNE
  return (unsigned short)(u >> 16);
}
__device__ __forceinline__ float b2f(unsigned short u) {
  union { unsigned int u; float f; } v; v.u = ((unsigned int)u) << 16; return v.f;
}

// Shared loc-block body: given box features for n (uniform) and per-lane m,
// build B-frags (features 8g..8g+8 of m) and MFMA against in-register W.
// Returns via L store. Used by both loc variants.
struct LocN {
  float cxn, cyn, rwn, rhn, lwn, lhn;
};

__device__ __forceinline__ void loc_body(int n, int m0, int w, int g, int c,
                                         const LocN& q,
                                         const float* __restrict__ locs,
                                         const float* __restrict__ lwt,  // lw table or null
                                         const float* __restrict__ lht,
                                         const float* __restrict__ cxt,
                                         const float* __restrict__ cyt,
                                         const float* __restrict__ wloc,
                                         const float* __restrict__ bloc,
                                         unsigned short* __restrict__ L) {
  // loop-invariant per-lane angles: ANG[t] = 100 * 1000^(-t/8)
  float ang0 = 100.0f * exp2f(-1.2457230355894468f * (float)g);  // t = g
  float ang1 = ang0 * 0.031622776601683794f;                     // t = g+4

  // A-frags from wloc (2KB, cache-hot): row c = head (>=8 zero padding),
  // feature f = 2*(4t+j)+sc maps to wloc feature j*16 + sc*8 + t.
  union AU { unsigned short us[8]; short8v v; } alo, ahi;
#pragma unroll
  for (int e = 0; e < 8; ++e) {
    int f0 = 8 * g + e;
    int f1 = 32 + 8 * g + e;
    int sc0 = f0 & 1, j0 = (f0 >> 1) & 3, tt0 = f0 >> 3;
    int sc1 = f1 & 1, j1 = (f1 >> 1) & 3, tt1 = f1 >> 3;
    alo.us[e] = (c < 8) ? f2bf(wloc[c * 64 + j0 * 16 + sc0 * 8 + tt0]) : (unsigned short)0;
    ahi.us[e] = (c < 8) ? f2bf(wloc[c * 64 + j1 * 16 + sc1 * 8 + tt1]) : (unsigned short)0;
  }
  float br_[4];
#pragma unroll
  for (int r = 0; r < 4; ++r) br_[r] = bloc[(4 * g + r) & 7];

#pragma unroll
  for (int it = 0; it < 4; ++it) {
    int m = m0 + w * 64 + it * 16 + c;
    float cxm, cym, lwm, lhm;
    if (lwt) {  // table-based (k2): box features precomputed in k1's prep
      cxm = cxt[m]; cym = cyt[m]; lwm = lwt[m]; lhm = lht[m];
    } else {    // self-contained (k1)
      float4 bm = reinterpret_cast<const float4*>(locs)[m];
      float wm = bm.z - bm.x + 1.0f;
      float hm = bm.w - bm.y + 1.0f;
      cxm = 0.5f * (bm.x + bm.z);
      cym = 0.5f * (bm.y + bm.w);
      lwm = __logf(wm);
      lhm = __logf(hm);
    }
    float dx = __logf(fmaxf(fabsf((q.cxn - cxm) * q.rwn), 1e-3f));
    float dy = __logf(fmaxf(fabsf((q.cyn - cym) * q.rhn), 1e-3f));
    float dwv = lwm - q.lwn;
    float dhv = lhm - q.lhn;
    float pos[4] = {dx, dy, dwv, dhv};

    // B-frags: element order within slice = [sin j, cos j] pairs, j=0..3
    union BU { unsigned int u[4]; short8v v; } b0, b1;
#pragma unroll
    for (int j = 0; j < 4; ++j) {
      float s0v, c0v, s1v, c1v;
      __sincosf(pos[j] * ang0, &s0v, &c0v);
      __sincosf(pos[j] * ang1, &s1v, &c1v);
      union { __hip_bfloat162 h; unsigned int u; } cv0, cv1;
      cv0.h = __float22bfloat162_rn(make_float2(s0v, c0v));
      cv1.h = __float22bfloat162_rn(make_float2(s1v, c1v));
      b0.u[j] = cv0.u;
      b1.u[j] = cv1.u;
    }

    f32x4 z = {0.f, 0.f, 0.f, 0.f};
    f32x4 acc4 = __builtin_amdgcn_mfma_f32_16x16x32_bf16(alo.v, b0.v, z, 0, 0, 0);
    acc4 = __builtin_amdgcn_mfma_f32_16x16x32_bf16(ahi.v, b1.v, acc4, 0, 0, 0);

    if (g < 2) {
#pragma unroll
      for (int r = 0; r < 4; ++r) {
        float v = fmaxf(acc4[r] + br_[r], 0.0f) + 1e-6f;
        L[((size_t)(4 * g + r) * NN + n) * NN + m] = f2bf(v);
      }
    }
  }
}

// ---------------- K1: cvt blocks + prep block + loc[0..LOCA) --------------
__global__ __launch_bounds__(256) void k1_cvtloc(const float* __restrict__ x,
                                                 const float* __restrict__ wq,
                                                 const float* __restrict__ locs,
                                                 const float* __restrict__ wloc,
                                                 const float* __restrict__ bloc,
                                                 unsigned short* __restrict__ xb,
                                                 unsigned short* __restrict__ wb,
                                                 float* __restrict__ bf,
                                                 unsigned short* __restrict__ L) {
  int blk = blockIdx.x;
  int tid = threadIdx.x;

  if (blk < CVT_BLOCKS) {
    // ---- cvt block: f32 -> bf16 for x and Wqkv (convert ONCE) ----
    constexpr int XTOT = NN * CDIM;  // 524288
    int idx = (blk * 256 + tid) * 4;
    if (idx < XTOT) {
      float4 v = *reinterpret_cast<const float4*>(x + idx);
      ushort4 o;
      o.x = f2bf(v.x); o.y = f2bf(v.y); o.z = f2bf(v.z); o.w = f2bf(v.w);
      *reinterpret_cast<ushort4*>(xb + idx) = o;
    } else {
      int j = idx - XTOT;
      float4 v = *reinterpret_cast<const float4*>(wq + j);
      ushort4 o;
      o.x = f2bf(v.x); o.y = f2bf(v.y); o.z = f2bf(v.z); o.w = f2bf(v.w);
      *reinterpret_cast<ushort4*>(wb + j) = o;
    }
  } else if (blk == CVT_BLOCKS) {
    // ---- prep: box feature tables (consumed by k2's loc blocks) ----
    for (int i = tid; i < NN; i += 256) {
      float4 b4 = reinterpret_cast<const float4*>(locs)[i];
      float w = b4.z - b4.x + 1.0f;
      float h = b4.w - b4.y + 1.0f;
      bf[0 * NN + i] = 0.5f * (b4.x + b4.z);  // cx
      bf[1 * NN + i] = 0.5f * (b4.y + b4.w);  // cy
      bf[2 * NN + i] = w;
      bf[3 * NN + i] = h;
      bf[4 * NN + i] = logf(w);
      bf[5 * NN + i] = logf(h);
    }
  } else {
    // ---- loc block (self-contained): lb in [0, LOCA) ----
    int lb = blk - CVT_BLOCKS - 1;
    int n = lb >> 2;
    int m0 = (lb & 3) * 256;
    int w = tid >> 6, l = tid & 63, g = l >> 4, c = l & 15;

    float4 bn = reinterpret_cast<const float4*>(locs)[n];
    float wn = bn.z - bn.x + 1.0f;
    float hn = bn.w - bn.y + 1.0f;
    LocN q;
    q.cxn = 0.5f * (bn.x + bn.z);
    q.cyn = 0.5f * (bn.y + bn.w);
    q.rwn = 1.0f / wn;
    q.rhn = 1.0f / hn;
    q.lwn = __logf(wn);
    q.lhn = __logf(hn);

    loc_body(n, m0, w, g, c, q, locs, nullptr, nullptr, nullptr, nullptr,
             wloc, bloc, L);
  }
}

// ---------------- K2: proj blocks + loc[LOCA..4096) -----------------------
__global__ __launch_bounds__(256) void k2_projloc(const unsigned short* __restrict__ xb,
                                                  const unsigned short* __restrict__ wb,
                                                  unsigned short* __restrict__ qk_bf,
                                                  unsigned short* __restrict__ vt,
                                                  const float* __restrict__ bf,
                                                  const float* __restrict__ locs,
                                                  const float* __restrict__ wloc,
                                                  const float* __restrict__ bloc,
                                                  unsigned short* __restrict__ L) {
  __shared__ unsigned short A_lds[64][72];
  __shared__ unsigned short B_lds[64][72];
  int blk = blockIdx.x;
  int tid = threadIdx.x;

  if (blk >= PROJ_BLOCKS) {
    // ---- loc block (table-based): lb in [LOCA, 4096) ----
    int lb = LOCA + (blk - PROJ_BLOCKS);
    int n = lb >> 2;
    int m0 = (lb & 3) * 256;
    int w = tid >> 6, l = tid & 63, g = l >> 4, c = l & 15;

    LocN q;
    q.cxn = bf[n];
    q.cyn = bf[NN + n];
    q.rwn = 1.0f / bf[2 * NN + n];
    q.rhn = 1.0f / bf[3 * NN + n];
    q.lwn = bf[4 * NN + n];
    q.lhn = bf[5 * NN + n];

    loc_body(n, m0, w, g, c, q, locs, bf + 4 * NN, bf + 5 * NN, bf, bf + NN,
             wloc, bloc, L);
  } else {
    // ---- projection gemm tile ----
    int t = blk;
    int n0 = (t & 15) * 64, i0 = (t >> 4) * 64;
    int w = tid >> 6, l = tid & 63, g = l >> 4, c = l & 15;
    int sr = tid >> 2;            // stage row 0..63
    int sc = (tid & 3) * 16;      // stage col (u16)

    f32x4 acc[4];
#pragma unroll
    for (int ct = 0; ct < 4; ++ct) acc[ct] = (f32x4){0.f, 0.f, 0.f, 0.f};

    for (int kt = 0; kt < CDIM; kt += 64) {
      const unsigned short* asrc = xb + (size_t)(n0 + sr) * CDIM + kt + sc;
      const unsigned short* bsrc = wb + (size_t)(i0 + sr) * CDIM + kt + sc;
      *reinterpret_cast<short8v*>(&A_lds[sr][sc])     = *reinterpret_cast<const short8v*>(asrc);
      *reinterpret_cast<short8v*>(&A_lds[sr][sc + 8]) = *reinterpret_cast<const short8v*>(asrc + 8);
      *reinterpret_cast<short8v*>(&B_lds[sr][sc])     = *reinterpret_cast<const short8v*>(bsrc);
      *reinterpret_cast<short8v*>(&B_lds[sr][sc + 8]) = *reinterpret_cast<const short8v*>(bsrc + 8);
      __syncthreads();
#pragma unroll
      for (int kks = 0; kks < 2; ++kks) {
        short8v a = *reinterpret_cast<const short8v*>(&A_lds[16 * w + c][kks * 32 + 8 * g]);
#pragma unroll
        for (int ct = 0; ct < 4; ++ct) {
          short8v b = *reinterpret_cast<const short8v*>(&B_lds[16 * ct + c][kks * 32 + 8 * g]);
          acc[ct] = __builtin_amdgcn_mfma_f32_16x16x32_bf16(a, b, acc[ct], 0, 0, 0);
        }
      }
      __syncthreads();
    }

    int s = i0 >> 9;            // 0=q, 1=k, 2=v
    int hh = (i0 >> 6) & 7;
    if (s < 2) {
      float scale = (s == 0) ? QSCALE : 1.0f;
      unsigned short* dst = qk_bf + ((size_t)(s * NH + hh) * NN) * HD;
#pragma unroll
      for (int ct = 0; ct < 4; ++ct)
#pragma unroll
        for (int r = 0; r < 4; ++r) {
          int n = n0 + 16 * w + 4 * g + r;
          dst[(size_t)n * HD + 16 * ct + c] = f2bf(acc[ct][r] * scale);
        }
    } else {
      // v: transpose 64x64 tile via LDS, write vt[h][d][n] coalesced
#pragma unroll
      for (int ct = 0; ct < 4; ++ct)
#pragma unroll
        for (int r = 0; r < 4; ++r) {
          A_lds[16 * w + 4 * g + r][16 * ct + c] = f2bf(acc[ct][r]);
        }
      __syncthreads();
      int d = tid >> 2;             // 0..63
      int nn0 = (tid & 3) * 16;     // 16-wide n chunk
      unsigned short o[16];
#pragma unroll
      for (int nn = 0; nn < 16; ++nn) o[nn] = A_lds[nn0 + nn][d];
      unsigned short* dst = vt + ((size_t)hh * HD + d) * NN + n0 + nn0;
      *reinterpret_cast<short8v*>(dst)     = *reinterpret_cast<short8v*>(&o[0]);
      *reinterpret_cast<short8v*>(dst + 8) = *reinterpret_cast<short8v*>(&o[8]);
    }
  }
}

// ---------------- K3: split-K MFMA flash attention ------------------------
// 8 waves per (16-q-rows, head) block; wave w owns 128 keys. V staged to LDS
// per wave; LDS phase-unioned {V,P} <-> {accs,mls,scw,rlf} (barrier-guarded).
__global__ __launch_bounds__(512) void k_mha(const unsigned short* __restrict__ qk,
                                             const unsigned short* __restrict__ vt,
                                             const unsigned short* __restrict__ L,
                                             float* __restrict__ out) {
  __shared__ short8v smem16[3200];  // 51200 B
  auto V = reinterpret_cast<unsigned short(*)[64][40]>(smem16);                      // [8], 40960B
  auto P = reinterpret_cast<unsigned short(*)[640]>(
      reinterpret_cast<char*>(smem16) + 40960);                                      // [8], 10240B
  auto accs = reinterpret_cast<float(*)[16][68]>(smem16);                            // [8], 34816B
  auto mls = reinterpret_cast<float(*)[2][16]>(reinterpret_cast<char*>(smem16) + 34816);
  auto scw2 = reinterpret_cast<float(*)[16]>(reinterpret_cast<char*>(smem16) + 35840); // [8][16]
  auto rlf = reinterpret_cast<float*>(reinterpret_cast<char*>(smem16) + 36352);        // [16]

  int tid = threadIdx.x;
  int w = tid >> 6;      // wave id: key-chunk
  int l = tid & 63;
  int g = l >> 4;        // 16-lane group: k-quarter index
  int c = l & 15;        // col within fragment
  int h = blockIdx.y;
  int n0 = blockIdx.x * 16;

  const unsigned short* qb = qk + ((size_t)(0 * NH + h) * NN + n0) * HD;
  const unsigned short* kb = qk + ((size_t)(1 * NH + h) * NN) * HD;
  const unsigned short* vb = vt + (size_t)h * HD * NN;
  const unsigned short* Lb = L + ((size_t)h * NN + n0 + 4 * g) * NN;  // row 4g (+r via r*NN)

  // Q A-frags (loop-invariant): row=c, k(hd)=8g+b
  short8v a_lo = *reinterpret_cast<const short8v*>(qb + (size_t)c * HD + 8 * g);
  short8v a_hi = *reinterpret_cast<const short8v*>(qb + (size_t)c * HD + 32 + 8 * g);

  f32x4 acc[4];
#pragma unroll
  for (int ct = 0; ct < 4; ++ct) acc[ct] = (f32x4){0.f, 0.f, 0.f, 0.f};
  float m_run[4] = {-3.0e38f, -3.0e38f, -3.0e38f, -3.0e38f};
  float l_run[4] = {0.f, 0.f, 0.f, 0.f};

#pragma unroll
  for (int it = 0; it < 4; ++it) {
    int mt = w * 128 + it * 32;

    // stage this wave's V tile: V[w][d][key], coalesced 64B-row loads from vt
#pragma unroll
    for (int p = 0; p < 4; ++p) {
      int d = p * 16 + (l >> 2);
      int key16 = (l & 3) * 8;
      *reinterpret_cast<short8v*>(&V[w][d][key16]) =
          *reinterpret_cast<const short8v*>(vb + (size_t)d * NN + mt + key16);
    }

    // loc factors t = relu(loc)+1e-6 (bf16): prefetch before softmax
    float t0[4], t1[4];
#pragma unroll
    for (int r = 0; r < 4; ++r) {
      t0[r] = b2f(Lb[(size_t)r * NN + mt + c]);
      t1[r] = b2f(Lb[(size_t)r * NN + mt + 16 + c]);
    }

    // K B-frags: col(key)=c, k(hd)=8g+b
    const unsigned short* k0p = kb + (size_t)(mt + c) * HD + 8 * g;
    const unsigned short* k1p = kb + (size_t)(mt + 16 + c) * HD + 8 * g;
    short8v b0_lo = *reinterpret_cast<const short8v*>(k0p);
    short8v b0_hi = *reinterpret_cast<const short8v*>(k0p + 32);
    short8v b1_lo = *reinterpret_cast<const short8v*>(k1p);
    short8v b1_hi = *reinterpret_cast<const short8v*>(k1p + 32);

    __builtin_amdgcn_s_setprio(1);
    f32x4 z = {0.f, 0.f, 0.f, 0.f};
    f32x4 s0 = __builtin_amdgcn_mfma_f32_16x16x32_bf16(a_lo, b0_lo, z, 0, 0, 0);
    s0 = __builtin_amdgcn_mfma_f32_16x16x32_bf16(a_hi, b0_hi, s0, 0, 0, 0);
    f32x4 s1 = __builtin_amdgcn_mfma_f32_16x16x32_bf16(a_lo, b1_lo, z, 0, 0, 0);
    s1 = __builtin_amdgcn_mfma_f32_16x16x32_bf16(a_hi, b1_hi, s1, 0, 0, 0);
    __builtin_amdgcn_s_setprio(0);

    // online softmax over s only (t folded in multiplicatively). l_run is kept
    // as a PER-LANE partial (sc[r] is row-uniform) — reduced once at stash.
    float sc[4], p0[4], p1[4];
#pragma unroll
    for (int r = 0; r < 4; ++r) {
      float mx = fmaxf(s0[r], s1[r]);
      mx = fmaxf(mx, __shfl_xor(mx, 1));
      mx = fmaxf(mx, __shfl_xor(mx, 2));
      mx = fmaxf(mx, __shfl_xor(mx, 4));
      mx = fmaxf(mx, __shfl_xor(mx, 8));
      float m_new = fmaxf(m_run[r], mx);
      sc[r] = __expf(m_run[r] - m_new);
      p0[r] = t0[r] * __expf(s0[r] - m_new);
      p1[r] = t1[r] * __expf(s1[r] - m_new);
      l_run[r] = l_run[r] * sc[r] + (p0[r] + p1[r]);
      m_run[r] = m_new;
    }
#pragma unroll
    for (int ct = 0; ct < 4; ++ct)
#pragma unroll
      for (int r = 0; r < 4; ++r) acc[ct][r] *= sc[r];

    // P -> LDS (bf16), D-layout positions
#pragma unroll
    for (int r = 0; r < 4; ++r) {
      P[w][(4 * g + r) * 40 + c] = f2bf(p0[r]);
      P[w][(4 * g + r) * 40 + 16 + c] = f2bf(p1[r]);
    }
    __builtin_amdgcn_wave_barrier();

    // PV: A = P[16 rows][32 keys] (row=c, k=8g+b), B = V_lds col-tiles
    short8v pa = *reinterpret_cast<const short8v*>(&P[w][c * 40 + 8 * g]);
    __builtin_amdgcn_s_setprio(1);
#pragma unroll
    for (int ct = 0; ct < 4; ++ct) {
      short8v vbf = *reinterpret_cast<const short8v*>(&V[w][ct * 16 + c][8 * g]);
      acc[ct] = __builtin_amdgcn_mfma_f32_16x16x32_bf16(pa, vbf, acc[ct], 0, 0, 0);
    }
    __builtin_amdgcn_s_setprio(0);
    __builtin_amdgcn_wave_barrier();  // LDS reads done before next-iter writes
  }

  // deferred l reduce across the 16 lanes of each group
#pragma unroll
  for (int r = 0; r < 4; ++r) {
    float ls = l_run[r];
    ls += __shfl_xor(ls, 1);
    ls += __shfl_xor(ls, 2);
    ls += __shfl_xor(ls, 4);
    ls += __shfl_xor(ls, 8);
    l_run[r] = ls;
  }

  __syncthreads();  // all waves done with V/P before accs/mls overlay writes

  // stash partials
  if (c == 0) {
#pragma unroll
    for (int r = 0; r < 4; ++r) {
      mls[w][0][4 * g + r] = m_run[r];
      mls[w][1][4 * g + r] = l_run[r];
    }
  }
#pragma unroll
  for (int ct = 0; ct < 4; ++ct)
#pragma unroll
    for (int r = 0; r < 4; ++r) accs[w][4 * g + r][ct * 16 + c] = acc[ct][r];
  __syncthreads();

  // per-row merge factors, computed once (was per-output: 64x redundant)
  if (tid < 16) {
    int row = tid;
    float mfin = mls[0][0][row];
#pragma unroll
    for (int w2i = 1; w2i < 8; ++w2i) mfin = fmaxf(mfin, mls[w2i][0][row]);
    float lfin = 0.f;
#pragma unroll
    for (int w2i = 0; w2i < 8; ++w2i) {
      float scv = __expf(mls[w2i][0][row] - mfin);
      scw2[w2i][row] = scv;
      lfin += mls[w2i][1][row] * scv;
    }
    rlf[row] = 1.0f / lfin;
  }
  __syncthreads();

  // merge: 1024 outputs over 512 threads (2 each)
#pragma unroll
  for (int o = tid; o < 16 * 64; o += 512) {
    int row = o >> 6, col = o & 63;
    float val = 0.f;
#pragma unroll
    for (int w2i = 0; w2i < 8; ++w2i) {
      val += scw2[w2i][row] * accs[w2i][row][col];
    }
    out[(size_t)(n0 + row) * CDIM + h * HD + col] = val * rlf[row];
  }
}

extern "C" void kernel_launch(void* const* d_in, const int* in_sizes, int n_in,
                              void* d_out, int out_size, void* d_ws, size_t ws_size,
                              hipStream_t stream) {
  const float* x    = (const float*)d_in[0];
  // d_in[1] = x_reg: unused by the reference
  const float* locs = (const float*)d_in[2];
  const float* wqkv = (const float*)d_in[3];
  const float* wloc = (const float*)d_in[4];
  const float* bloc = (const float*)d_in[5];
  float* out = (float*)d_out;
  float* ws = (float*)d_ws;
  unsigned short* ws_u16 = (unsigned short*)d_ws;

  unsigned short* qk_bf = ws_u16 + QKBF_OFF_U16;
  unsigned short* vt_bf = ws_u16 + VT_OFF_U16;
  unsigned short* xb    = ws_u16 + XB_OFF_U16;
  unsigned short* wb    = ws_u16 + WB_OFF_U16;
  unsigned short* L     = ws_u16 + L_OFF_U16;
  float* bf = ws + BF_OFF_F32;

  k1_cvtloc<<<dim3(CVT_BLOCKS + 1 + LOCA), dim3(256), 0, stream>>>(
      x, wqkv, locs, wloc, bloc, xb, wb, bf, L);
  k2_projloc<<<dim3(PROJ_BLOCKS + (LOC_TOTAL - LOCA)), dim3(256), 0, stream>>>(
      xb, wb, qk_bf, vt_bf, bf, locs, wloc, bloc, L);
  k_mha<<<dim3(NN / 16, NH), dim3(512), 0, stream>>>(qk_bf, vt_bf, L, out);
}

// Round 10
// 50.254 us; speedup vs baseline: 3.6724x; 1.2740x over previous
//
#include <hip/hip_runtime.h>
#include <hip/hip_bf16.h>

// SelfAttentionLocal: N=1024, DIM=512, H=8, hd=64. Inputs f32, output f32.
// 3 kernels: [prep+cvt] -> [mid: proj-gemm blocks FIRST then loc blocks
// (independent, co-scheduled)] -> [split-K MFMA flash].
// L stores t = relu(loc)+1e-6 (not log t); k_mha multiplies t after the exp.
// R10 = R7 verbatim (best verified: 50.46us). R8 (intra-grid flag spin:
// acquire-invalidate traffic poisoned co-tenant caches, 174us) and R9
// (kernel-split of loc: tripled mid-phase cost, 64us) both reverted.
// Loc head-projection on MFMA with shuffle-free/LDS-free fragment build:
// lane (g,c) computes features [8g,8g+8) of m=m_base+c (t=g / t=g+4, j=0..3)
// directly in B-frag order via __float22bfloat162_rn; A = W_loc[16x64] bf16.

namespace {
constexpr int NN   = 1024;
constexpr int CDIM = 512;
constexpr int NH   = 8;
constexpr int HD   = 64;
constexpr int NOUT = 3 * CDIM;  // 1536 projection output features
constexpr int PROJ_BLOCKS = (NN / 64) * (NOUT / 64);  // 384
constexpr float QSCALE = 0.125f;  // (512/8)^-0.5

// ws layout (u16 units, then f32 region)
constexpr size_t QKBF_OFF_U16 = 0;                                   // 2*8*1024*64
constexpr size_t VT_OFF_U16   = (size_t)2 * NH * NN * HD;            // [h][d][n]
constexpr size_t XB_OFF_U16   = VT_OFF_U16 + (size_t)NH * HD * NN;
constexpr size_t WB_OFF_U16   = XB_OFF_U16 + (size_t)NN * CDIM;
constexpr size_t L_OFF_U16    = WB_OFF_U16 + (size_t)NOUT * CDIM;    // 2,883,584
constexpr size_t END_U16      = L_OFF_U16 + (size_t)NH * NN * NN;    // 11,272,192
constexpr size_t BF_OFF_F32   = END_U16 / 2;                         // 5,636,096
constexpr size_t WR_OFF_F32   = BF_OFF_F32 + 6 * NN;
constexpr size_t W2_OFF_U16   = 2 * (WR_OFF_F32 + 528);              // [16][64] bf16
}

typedef __attribute__((ext_vector_type(8))) short short8v;   // 8 bf16 (4 VGPR)
typedef __attribute__((ext_vector_type(4))) float f32x4;

__device__ __forceinline__ unsigned short f2bf(float f) {
  union { float f; unsigned int u; } v; v.f = f;
  unsigned int u = v.u;
  u += 0x7fffu + ((u >> 16) & 1u);  // RNE
  return (unsigned short)(u >> 16);
}
__device__ __forceinline__ float b2f(unsigned short u) {
  union { unsigned int u; float f; } v; v.u = ((unsigned int)u) << 16; return v.f;
}

// ---------------- K1: bf16 convert of x/Wqkv + box features + W repacks ----
__global__ __launch_bounds__(256) void k_cvt(const float* __restrict__ x,
                                             const float* __restrict__ wq,
                                             const float* __restrict__ locs,
                                             const float* __restrict__ wloc,
                                             const float* __restrict__ bloc,
                                             unsigned short* __restrict__ xb,
                                             unsigned short* __restrict__ wb,
                                             float* __restrict__ bf,
                                             float* __restrict__ wr,
                                             unsigned short* __restrict__ w2) {
  constexpr int XTOT = NN * CDIM;           // 524288
  constexpr int CVT_BLOCKS = 1280;          // (XTOT + NOUT*CDIM)/1024
  int b = blockIdx.x;
  int tid = threadIdx.x;
  if (b < CVT_BLOCKS) {
    int idx = (b * 256 + tid) * 4;
    if (idx < XTOT) {
      float4 v = *reinterpret_cast<const float4*>(x + idx);
      ushort4 o;
      o.x = f2bf(v.x); o.y = f2bf(v.y); o.z = f2bf(v.z); o.w = f2bf(v.w);
      *reinterpret_cast<ushort4*>(xb + idx) = o;
    } else {
      int j = idx - XTOT;
      float4 v = *reinterpret_cast<const float4*>(wq + j);
      ushort4 o;
      o.x = f2bf(v.x); o.y = f2bf(v.y); o.z = f2bf(v.z); o.w = f2bf(v.w);
      *reinterpret_cast<ushort4*>(wb + j) = o;
    }
  } else {
    // prep: box features + W_loc repacks + bias
    for (int i = tid; i < NN; i += 256) {
      float4 b4 = reinterpret_cast<const float4*>(locs)[i];
      float x1 = b4.x, y1 = b4.y, x2 = b4.z, y2 = b4.w;
      float w = x2 - x1 + 1.0f;
      float h = y2 - y1 + 1.0f;
      bf[0 * NN + i] = 0.5f * (x1 + x2);  // cx
      bf[1 * NN + i] = 0.5f * (y1 + y2);  // cy
      bf[2 * NN + i] = w;
      bf[3 * NN + i] = h;
      bf[4 * NN + i] = logf(w);
      bf[5 * NN + i] = logf(h);
    }
    if (tid < 8) wr[512 + tid] = bloc[tid];
    // w2[h][f] bf16, heads padded to 16 (zero). f = 2*(t*4+j) + sc maps to
    // reference feature j*16 + sc*8 + t  (emb = concat(sin, cos) over nf=8).
    for (int i = tid; i < 16 * 64; i += 256) {
      int hh = i >> 6, f = i & 63;
      int sc = f & 1, tj = f >> 1, j = tj & 3, t = tj >> 2;
      float v = (hh < 8) ? wloc[hh * 64 + j * 16 + sc * 8 + t] : 0.0f;
      w2[i] = f2bf(v);
    }
  }
}

// ---------------- K2: union kernel — proj blocks (0..383) + loc blocks ---
// proj: LDS-staged 64x64 MFMA gemm tile; q/k row-major, v transposed via LDS.
// loc: per wave-iter, 16 m x 8 heads via 2 MFMA; lane (g,c) builds its own
// B-frag slice (features 8g..8g+8 of m=m_base+c) = {t=g or g+4, j=0..3}.
__global__ __launch_bounds__(256) void k_mid(const unsigned short* __restrict__ xb,
                                             const unsigned short* __restrict__ wb,
                                             unsigned short* __restrict__ qk_bf,
                                             unsigned short* __restrict__ vt,
                                             const float* __restrict__ bf,
                                             const float* __restrict__ wr,
                                             const unsigned short* __restrict__ w2,
                                             unsigned short* __restrict__ L) {
  __shared__ unsigned short A_lds[64][72];
  __shared__ unsigned short B_lds[64][72];
  int blk = blockIdx.x;
  int tid = threadIdx.x;

  if (blk >= PROJ_BLOCKS) {
    // ---- loc block: one n-row, 256 m; wave w owns m in [m0+64w, +64) ----
    int blk2 = blk - PROJ_BLOCKS;
    int n = blk2 >> 2;
    int m0 = (blk2 & 3) * 256;
    int w = tid >> 6, l = tid & 63, g = l >> 4, c = l & 15;

    const float* cx = bf;
    const float* cy = bf + NN;
    const float* lw = bf + 4 * NN;
    const float* lh = bf + 5 * NN;

    float cxn = cx[n], cyn = cy[n];
    float rwn = 1.0f / bf[2 * NN + n];
    float rhn = 1.0f / bf[3 * NN + n];
    float lwn = lw[n], lhn = lh[n];

    // loop-invariant per-lane angles: ANG[t] = 100 * 1000^(-t/8)
    float ang0 = 100.0f * exp2f(-1.2457230355894468f * (float)g);  // t = g
    float ang1 = ang0 * 0.031622776601683794f;                     // t = g+4

    // A-frags: W2 rows = heads (padded to 16); lane row = c, k-slice 8g
    short8v aw_lo = *reinterpret_cast<const short8v*>(w2 + c * 64 + 8 * g);
    short8v aw_hi = *reinterpret_cast<const short8v*>(w2 + c * 64 + 32 + 8 * g);
    // bias per D-row: head = 4g + r (rows 8..15 padding, masked at store)
    float br_[4];
#pragma unroll
    for (int r = 0; r < 4; ++r) br_[r] = wr[512 + ((4 * g + r) & 7)];

#pragma unroll
    for (int it = 0; it < 4; ++it) {
      int m = m0 + w * 64 + it * 16 + c;
      float dx = __logf(fmaxf(fabsf((cxn - cx[m]) * rwn), 1e-3f));
      float dy = __logf(fmaxf(fabsf((cyn - cy[m]) * rhn), 1e-3f));
      float dwv = lw[m] - lwn;
      float dhv = lh[m] - lhn;
      float pos[4] = {dx, dy, dwv, dhv};

      // B-frags: element order within slice = [sin j, cos j] pairs, j=0..3
      union BU { unsigned int u[4]; short8v v; } b0, b1;
#pragma unroll
      for (int j = 0; j < 4; ++j) {
        float s0v, c0v, s1v, c1v;
        __sincosf(pos[j] * ang0, &s0v, &c0v);
        __sincosf(pos[j] * ang1, &s1v, &c1v);
        union { __hip_bfloat162 h; unsigned int u; } cv0, cv1;
        cv0.h = __float22bfloat162_rn(make_float2(s0v, c0v));
        cv1.h = __float22bfloat162_rn(make_float2(s1v, c1v));
        b0.u[j] = cv0.u;
        b1.u[j] = cv1.u;
      }

      f32x4 z = {0.f, 0.f, 0.f, 0.f};
      f32x4 acc4 = __builtin_amdgcn_mfma_f32_16x16x32_bf16(aw_lo, b0.v, z, 0, 0, 0);
      acc4 = __builtin_amdgcn_mfma_f32_16x16x32_bf16(aw_hi, b1.v, acc4, 0, 0, 0);

      if (g < 2) {
#pragma unroll
        for (int r = 0; r < 4; ++r) {
          float v = fmaxf(acc4[r] + br_[r], 0.0f) + 1e-6f;
          L[((size_t)(4 * g + r) * NN + n) * NN + m] = f2bf(v);
        }
      }
    }
  } else {
    // ---- projection gemm tile ----
    int t = blk;
    int n0 = (t & 15) * 64, i0 = (t >> 4) * 64;
    int w = tid >> 6, l = tid & 63, g = l >> 4, c = l & 15;
    int sr = tid >> 2;            // stage row 0..63
    int sc = (tid & 3) * 16;      // stage col (u16)

    f32x4 acc[4];
#pragma unroll
    for (int ct = 0; ct < 4; ++ct) acc[ct] = (f32x4){0.f, 0.f, 0.f, 0.f};

    for (int kt = 0; kt < CDIM; kt += 64) {
      const unsigned short* asrc = xb + (size_t)(n0 + sr) * CDIM + kt + sc;
      const unsigned short* bsrc = wb + (size_t)(i0 + sr) * CDIM + kt + sc;
      *reinterpret_cast<short8v*>(&A_lds[sr][sc])     = *reinterpret_cast<const short8v*>(asrc);
      *reinterpret_cast<short8v*>(&A_lds[sr][sc + 8]) = *reinterpret_cast<const short8v*>(asrc + 8);
      *reinterpret_cast<short8v*>(&B_lds[sr][sc])     = *reinterpret_cast<const short8v*>(bsrc);
      *reinterpret_cast<short8v*>(&B_lds[sr][sc + 8]) = *reinterpret_cast<const short8v*>(bsrc + 8);
      __syncthreads();
#pragma unroll
      for (int kks = 0; kks < 2; ++kks) {
        short8v a = *reinterpret_cast<const short8v*>(&A_lds[16 * w + c][kks * 32 + 8 * g]);
#pragma unroll
        for (int ct = 0; ct < 4; ++ct) {
          short8v b = *reinterpret_cast<const short8v*>(&B_lds[16 * ct + c][kks * 32 + 8 * g]);
          acc[ct] = __builtin_amdgcn_mfma_f32_16x16x32_bf16(a, b, acc[ct], 0, 0, 0);
        }
      }
      __syncthreads();
    }

    int s = i0 >> 9;            // 0=q, 1=k, 2=v
    int hh = (i0 >> 6) & 7;
    if (s < 2) {
      float scale = (s == 0) ? QSCALE : 1.0f;
      unsigned short* dst = qk_bf + ((size_t)(s * NH + hh) * NN) * HD;
#pragma unroll
      for (int ct = 0; ct < 4; ++ct)
#pragma unroll
        for (int r = 0; r < 4; ++r) {
          int n = n0 + 16 * w + 4 * g + r;
          dst[(size_t)n * HD + 16 * ct + c] = f2bf(acc[ct][r] * scale);
        }
    } else {
      // v: transpose 64x64 tile via LDS, write vt[h][d][n] coalesced
#pragma unroll
      for (int ct = 0; ct < 4; ++ct)
#pragma unroll
        for (int r = 0; r < 4; ++r) {
          A_lds[16 * w + 4 * g + r][16 * ct + c] = f2bf(acc[ct][r]);
        }
      __syncthreads();
      int d = tid >> 2;             // 0..63
      int nn0 = (tid & 3) * 16;     // 16-wide n chunk
      unsigned short o[16];
#pragma unroll
      for (int nn = 0; nn < 16; ++nn) o[nn] = A_lds[nn0 + nn][d];
      unsigned short* dst = vt + ((size_t)hh * HD + d) * NN + n0 + nn0;
      *reinterpret_cast<short8v*>(dst)     = *reinterpret_cast<short8v*>(&o[0]);
      *reinterpret_cast<short8v*>(dst + 8) = *reinterpret_cast<short8v*>(&o[8]);
    }
  }
}

// ---------------- K3: split-K MFMA flash attention ------------------------
// 8 waves per (16-q-rows, head) block; wave w owns 128 keys. V staged to LDS
// per wave; LDS phase-unioned {V,P} <-> {accs,mls,scw,rlf} (barrier-guarded).
__global__ __launch_bounds__(512) void k_mha(const unsigned short* __restrict__ qk,
                                             const unsigned short* __restrict__ vt,
                                             const unsigned short* __restrict__ L,
                                             float* __restrict__ out) {
  __shared__ short8v smem16[3200];  // 51200 B
  auto V = reinterpret_cast<unsigned short(*)[64][40]>(smem16);                      // [8], 40960B
  auto P = reinterpret_cast<unsigned short(*)[640]>(
      reinterpret_cast<char*>(smem16) + 40960);                                      // [8], 10240B
  auto accs = reinterpret_cast<float(*)[16][68]>(smem16);                            // [8], 34816B
  auto mls = reinterpret_cast<float(*)[2][16]>(reinterpret_cast<char*>(smem16) + 34816);
  auto scw2 = reinterpret_cast<float(*)[16]>(reinterpret_cast<char*>(smem16) + 35840); // [8][16]
  auto rlf = reinterpret_cast<float*>(reinterpret_cast<char*>(smem16) + 36352);        // [16]

  int tid = threadIdx.x;
  int w = tid >> 6;      // wave id: key-chunk
  int l = tid & 63;
  int g = l >> 4;        // 16-lane group: k-quarter index
  int c = l & 15;        // col within fragment
  int h = blockIdx.y;
  int n0 = blockIdx.x * 16;

  const unsigned short* qb = qk + ((size_t)(0 * NH + h) * NN + n0) * HD;
  const unsigned short* kb = qk + ((size_t)(1 * NH + h) * NN) * HD;
  const unsigned short* vb = vt + (size_t)h * HD * NN;
  const unsigned short* Lb = L + ((size_t)h * NN + n0 + 4 * g) * NN;  // row 4g (+r via r*NN)

  // Q A-frags (loop-invariant): row=c, k(hd)=8g+b
  short8v a_lo = *reinterpret_cast<const short8v*>(qb + (size_t)c * HD + 8 * g);
  short8v a_hi = *reinterpret_cast<const short8v*>(qb + (size_t)c * HD + 32 + 8 * g);

  f32x4 acc[4];
#pragma unroll
  for (int ct = 0; ct < 4; ++ct) acc[ct] = (f32x4){0.f, 0.f, 0.f, 0.f};
  float m_run[4] = {-3.0e38f, -3.0e38f, -3.0e38f, -3.0e38f};
  float l_run[4] = {0.f, 0.f, 0.f, 0.f};

#pragma unroll
  for (int it = 0; it < 4; ++it) {
    int mt = w * 128 + it * 32;

    // stage this wave's V tile: V[w][d][key], coalesced 64B-row loads from vt
#pragma unroll
    for (int p = 0; p < 4; ++p) {
      int d = p * 16 + (l >> 2);
      int key16 = (l & 3) * 8;
      *reinterpret_cast<short8v*>(&V[w][d][key16]) =
          *reinterpret_cast<const short8v*>(vb + (size_t)d * NN + mt + key16);
    }

    // loc factors t = relu(loc)+1e-6 (bf16): prefetch before softmax
    float t0[4], t1[4];
#pragma unroll
    for (int r = 0; r < 4; ++r) {
      t0[r] = b2f(Lb[(size_t)r * NN + mt + c]);
      t1[r] = b2f(Lb[(size_t)r * NN + mt + 16 + c]);
    }

    // K B-frags: col(key)=c, k(hd)=8g+b
    const unsigned short* k0p = kb + (size_t)(mt + c) * HD + 8 * g;
    const unsigned short* k1p = kb + (size_t)(mt + 16 + c) * HD + 8 * g;
    short8v b0_lo = *reinterpret_cast<const short8v*>(k0p);
    short8v b0_hi = *reinterpret_cast<const short8v*>(k0p + 32);
    short8v b1_lo = *reinterpret_cast<const short8v*>(k1p);
    short8v b1_hi = *reinterpret_cast<const short8v*>(k1p + 32);

    __builtin_amdgcn_s_setprio(1);
    f32x4 z = {0.f, 0.f, 0.f, 0.f};
    f32x4 s0 = __builtin_amdgcn_mfma_f32_16x16x32_bf16(a_lo, b0_lo, z, 0, 0, 0);
    s0 = __builtin_amdgcn_mfma_f32_16x16x32_bf16(a_hi, b0_hi, s0, 0, 0, 0);
    f32x4 s1 = __builtin_amdgcn_mfma_f32_16x16x32_bf16(a_lo, b1_lo, z, 0, 0, 0);
    s1 = __builtin_amdgcn_mfma_f32_16x16x32_bf16(a_hi, b1_hi, s1, 0, 0, 0);
    __builtin_amdgcn_s_setprio(0);

    // online softmax over s only (t folded in multiplicatively). l_run is kept
    // as a PER-LANE partial (sc[r] is row-uniform) — reduced once at stash.
    float sc[4], p0[4], p1[4];
#pragma unroll
    for (int r = 0; r < 4; ++r) {
      float mx = fmaxf(s0[r], s1[r]);
      mx = fmaxf(mx, __shfl_xor(mx, 1));
      mx = fmaxf(mx, __shfl_xor(mx, 2));
      mx = fmaxf(mx, __shfl_xor(mx, 4));
      mx = fmaxf(mx, __shfl_xor(mx, 8));
      float m_new = fmaxf(m_run[r], mx);
      sc[r] = __expf(m_run[r] - m_new);
      p0[r] = t0[r] * __expf(s0[r] - m_new);
      p1[r] = t1[r] * __expf(s1[r] - m_new);
      l_run[r] = l_run[r] * sc[r] + (p0[r] + p1[r]);
      m_run[r] = m_new;
    }
#pragma unroll
    for (int ct = 0; ct < 4; ++ct)
#pragma unroll
      for (int r = 0; r < 4; ++r) acc[ct][r] *= sc[r];

    // P -> LDS (bf16), D-layout positions
#pragma unroll
    for (int r = 0; r < 4; ++r) {
      P[w][(4 * g + r) * 40 + c] = f2bf(p0[r]);
      P[w][(4 * g + r) * 40 + 16 + c] = f2bf(p1[r]);
    }
    __builtin_amdgcn_wave_barrier();

    // PV: A = P[16 rows][32 keys] (row=c, k=8g+b), B = V_lds col-tiles
    short8v pa = *reinterpret_cast<const short8v*>(&P[w][c * 40 + 8 * g]);
    __builtin_amdgcn_s_setprio(1);
#pragma unroll
    for (int ct = 0; ct < 4; ++ct) {
      short8v vbf = *reinterpret_cast<const short8v*>(&V[w][ct * 16 + c][8 * g]);
      acc[ct] = __builtin_amdgcn_mfma_f32_16x16x32_bf16(pa, vbf, acc[ct], 0, 0, 0);
    }
    __builtin_amdgcn_s_setprio(0);
    __builtin_amdgcn_wave_barrier();  // LDS reads done before next-iter writes
  }

  // deferred l reduce across the 16 lanes of each group
#pragma unroll
  for (int r = 0; r < 4; ++r) {
    float ls = l_run[r];
    ls += __shfl_xor(ls, 1);
    ls += __shfl_xor(ls, 2);
    ls += __shfl_xor(ls, 4);
    ls += __shfl_xor(ls, 8);
    l_run[r] = ls;
  }

  __syncthreads();  // all waves done with V/P before accs/mls overlay writes

  // stash partials
  if (c == 0) {
#pragma unroll
    for (int r = 0; r < 4; ++r) {
      mls[w][0][4 * g + r] = m_run[r];
      mls[w][1][4 * g + r] = l_run[r];
    }
  }
#pragma unroll
  for (int ct = 0; ct < 4; ++ct)
#pragma unroll
    for (int r = 0; r < 4; ++r) accs[w][4 * g + r][ct * 16 + c] = acc[ct][r];
  __syncthreads();

  // per-row merge factors, computed once (was per-output: 64x redundant)
  if (tid < 16) {
    int row = tid;
    float mfin = mls[0][0][row];
#pragma unroll
    for (int w2i = 1; w2i < 8; ++w2i) mfin = fmaxf(mfin, mls[w2i][0][row]);
    float lfin = 0.f;
#pragma unroll
    for (int w2i = 0; w2i < 8; ++w2i) {
      float scv = __expf(mls[w2i][0][row] - mfin);
      scw2[w2i][row] = scv;
      lfin += mls[w2i][1][row] * scv;
    }
    rlf[row] = 1.0f / lfin;
  }
  __syncthreads();

  // merge: 1024 outputs over 512 threads (2 each)
#pragma unroll
  for (int o = tid; o < 16 * 64; o += 512) {
    int row = o >> 6, col = o & 63;
    float val = 0.f;
#pragma unroll
    for (int w2i = 0; w2i < 8; ++w2i) {
      val += scw2[w2i][row] * accs[w2i][row][col];
    }
    out[(size_t)(n0 + row) * CDIM + h * HD + col] = val * rlf[row];
  }
}

extern "C" void kernel_launch(void* const* d_in, const int* in_sizes, int n_in,
                              void* d_out, int out_size, void* d_ws, size_t ws_size,
                              hipStream_t stream) {
  const float* x    = (const float*)d_in[0];
  // d_in[1] = x_reg: unused by the reference
  const float* locs = (const float*)d_in[2];
  const float* wqkv = (const float*)d_in[3];
  const float* wloc = (const float*)d_in[4];
  const float* bloc = (const float*)d_in[5];
  float* out = (float*)d_out;
  float* ws = (float*)d_ws;
  unsigned short* ws_u16 = (unsigned short*)d_ws;

  unsigned short* qk_bf = ws_u16 + QKBF_OFF_U16;
  unsigned short* vt_bf = ws_u16 + VT_OFF_U16;
  unsigned short* xb    = ws_u16 + XB_OFF_U16;
  unsigned short* wb    = ws_u16 + WB_OFF_U16;
  unsigned short* L     = ws_u16 + L_OFF_U16;
  unsigned short* w2    = ws_u16 + W2_OFF_U16;
  float* bf = ws + BF_OFF_F32;
  float* wr = ws + WR_OFF_F32;

  k_cvt<<<dim3(1281), dim3(256), 0, stream>>>(x, wqkv, locs, wloc, bloc, xb, wb, bf, wr, w2);
  k_mid<<<dim3(PROJ_BLOCKS + 4096), dim3(256), 0, stream>>>(
      xb, wb, qk_bf, vt_bf, bf, wr, w2, L);
  k_mha<<<dim3(NN / 16, NH), dim3(512), 0, stream>>>(qk_bf, vt_bf, L, out);
}